// Round 10
// baseline (1353.349 us; speedup 1.0000x reference)
//
#include <hip/hip_runtime.h>
#include <hip/hip_fp16.h>
#include <hip/hip_cooperative_groups.h>

namespace cg = cooperative_groups;

#define B_ 4
#define N_ 8192
#define D_ 4096
#define E_ 64
#define M_ (B_ * N_)          // 32768 tokens
#define NK 64                 // 64 K-chunks of 64

typedef _Float16 half8 __attribute__((ext_vector_type(8)));
typedef float f32x4 __attribute__((ext_vector_type(4)));

union H4 { _Float16 h[4]; uint2 u2; };

// ---------------------------------------------------------------------------
// w (fp32 [E][D]) -> w16 (f16 [E][D]) once; L2-resident thereafter.
// ---------------------------------------------------------------------------
__global__ __launch_bounds__(256) void convert_w(const float* __restrict__ w,
                                                 _Float16* __restrict__ w16) {
  const int i = (blockIdx.x * 256 + threadIdx.x) * 4;
  const float4 v = *(const float4*)&w[i];
  H4 h;
  h.h[0] = (_Float16)v.x; h.h[1] = (_Float16)v.y;
  h.h[2] = (_Float16)v.z; h.h[3] = (_Float16)v.w;
  *(uint2*)&w16[i] = h.u2;
}

// ---------------------------------------------------------------------------
// GEMM (R9 verbatim — ties best at 218.4): 32-row tile, 256 thr, 4 blocks/CU,
// named-set depth-2 prefetch, ONE lgkm-only barrier per chunk.
// ---------------------------------------------------------------------------
__global__ __launch_bounds__(256, 4) void gemm_log(const float* __restrict__ x,
                                                   const _Float16* __restrict__ w16,
                                                   float* __restrict__ t0,
                                                   float* __restrict__ slot0) {
  __shared__ _Float16 As[2][32 * 64];
  __shared__ _Float16 Bs[2][64 * 64];
  __shared__ float wsum[4][32];

  const int tid = threadIdx.x;
  const int lane = tid & 63;
  const int wv = tid >> 6;
  const int wr = wv >> 1;
  const int wc = wv & 1;
  const int l15 = lane & 15;
  const int lq = lane >> 4;
  const int rowBase = blockIdx.x * 32;
  const int b = rowBase >> 13;

  const int sar = tid >> 3;
  const int sau = tid & 7;
  const float* xs = x + (size_t)(rowBase + sar) * D_ + sau * 8;
  const int sdstA = sar * 64 + ((sau ^ (sar & 7)) << 3);

  const int sbr = tid >> 2;
  const int sbu = (tid & 3) * 2;
  const _Float16* ws2 = w16 + (size_t)sbr * D_ + sbu * 8;
  const int sdstB0 = sbr * 64 + ((sbu ^ (sbr & 7)) << 3);
  const int sdstB1 = sbr * 64 + (((sbu + 1) ^ (sbr & 7)) << 3);

  const int arow = wr * 16 + l15;
  const int aoff0 = arow * 64 + ((lq ^ (arow & 7)) << 3);
  const int aoff1 = arow * 64 + (((4 + lq) ^ (arow & 7)) << 3);
  const int bcol0 = wc * 32 + l15;
  const int bcol1 = wc * 32 + 16 + l15;
  const int boff00 = bcol0 * 64 + ((lq ^ (bcol0 & 7)) << 3);
  const int boff01 = bcol0 * 64 + (((4 + lq) ^ (bcol0 & 7)) << 3);
  const int boff10 = bcol1 * 64 + ((lq ^ (bcol1 & 7)) << 3);
  const int boff11 = bcol1 * 64 + (((4 + lq) ^ (bcol1 & 7)) << 3);

  f32x4 acc0 = {}, acc1 = {};
  float4 ax0, ax1, cx0, cx1;
  half8 ab0, ab1, cb0, cb1;

  auto body = [&](float4& px0, float4& px1, half8& pb0, half8& pb1,
                  int buf, int kpref) {
    half8 hx;
    hx[0] = (_Float16)px0.x; hx[1] = (_Float16)px0.y;
    hx[2] = (_Float16)px0.z; hx[3] = (_Float16)px0.w;
    hx[4] = (_Float16)px1.x; hx[5] = (_Float16)px1.y;
    hx[6] = (_Float16)px1.z; hx[7] = (_Float16)px1.w;
    *(half8*)&As[buf][sdstA] = hx;
    *(half8*)&Bs[buf][sdstB0] = pb0;
    *(half8*)&Bs[buf][sdstB1] = pb1;
    if (kpref < NK) {
      const int o = kpref * 64;
      px0 = *(const float4*)(xs + o);
      px1 = *(const float4*)(xs + o + 4);
      pb0 = *(const half8*)(ws2 + o);
      pb1 = *(const half8*)(ws2 + o + 8);
    }
    asm volatile("s_waitcnt lgkmcnt(0)" ::: "memory");
    __builtin_amdgcn_s_barrier();
    half8 a0  = *(const half8*)&As[buf][aoff0];
    half8 a1  = *(const half8*)&As[buf][aoff1];
    half8 b00 = *(const half8*)&Bs[buf][boff00];
    half8 b01 = *(const half8*)&Bs[buf][boff01];
    half8 b10 = *(const half8*)&Bs[buf][boff10];
    half8 b11 = *(const half8*)&Bs[buf][boff11];
    acc0 = __builtin_amdgcn_mfma_f32_16x16x32_f16(a0, b00, acc0, 0, 0, 0);
    acc0 = __builtin_amdgcn_mfma_f32_16x16x32_f16(a1, b01, acc0, 0, 0, 0);
    acc1 = __builtin_amdgcn_mfma_f32_16x16x32_f16(a0, b10, acc1, 0, 0, 0);
    acc1 = __builtin_amdgcn_mfma_f32_16x16x32_f16(a1, b11, acc1, 0, 0, 0);
  };

  ax0 = *(const float4*)(xs);      ax1 = *(const float4*)(xs + 4);
  ab0 = *(const half8*)(ws2);      ab1 = *(const half8*)(ws2 + 8);
  cx0 = *(const float4*)(xs + 64); cx1 = *(const float4*)(xs + 68);
  cb0 = *(const half8*)(ws2 + 64); cb1 = *(const half8*)(ws2 + 72);

  for (int kc = 0; kc < NK; kc += 2) {
    body(ax0, ax1, ab0, ab1, 0, kc + 2);
    body(cx0, cx1, cb0, cb1, 1, kc + 3);
  }

  float ls0 = 0.f, ls1 = 0.f;
#pragma unroll
  for (int r = 0; r < 4; ++r) {
    const float v0 = fmaxf(acc0[r], 1e-6f);
    const float v1 = fmaxf(acc1[r], 1e-6f);
    const int grow = rowBase + wr * 16 + lq * 4 + r;
    t0[(size_t)grow * E_ + wc * 32 + l15] = __logf(v0);
    t0[(size_t)grow * E_ + wc * 32 + 16 + l15] = __logf(v1);
    ls0 += v0; ls1 += v1;
  }
  {
    float vv = ls0;
    vv += __shfl_xor(vv, 16); vv += __shfl_xor(vv, 32);
    if (lq == 0) wsum[wv][l15] = vv;
    vv = ls1;
    vv += __shfl_xor(vv, 16); vv += __shfl_xor(vv, 32);
    if (lq == 0) wsum[wv][16 + l15] = vv;
  }
  __syncthreads();
  if (tid < 64) {
    const int e = tid;
    const int half = e >> 5;
    const int idx = e & 31;
    const float tot = wsum[half][idx] + wsum[2 + half][idx];
    atomicAdd(&slot0[b * E_ + e], tot);
  }
}

// ---------------------------------------------------------------------------
// ALL 8 Sinkhorn iterations in ONE cooperative kernel. t0 in registers
// (8 floats/thread), 7 grid.sync()s, slots via device-scope atomics,
// output written once. Math identical to the proven per-iteration chain.
// ---------------------------------------------------------------------------
__global__ __launch_bounds__(256, 4) void sinkhorn_all(const float* __restrict__ t0,
                                                       float* __restrict__ slots,
                                                       float* __restrict__ out) {
  __shared__ float wsum[4][64];
  __shared__ float cbuf[64];
  const int tid = threadIdx.x;
  const int lane = tid & 63;
  const int wv = tid >> 6;
  const int b = blockIdx.x >> 8;
  const int chunk = blockIdx.x & 255;
  const size_t base = ((size_t)b * N_ + chunk * 32 + wv * 8) * E_ + lane;

  float t[8];
#pragma unroll
  for (int r = 0; r < 8; ++r) t[r] = t0[base + (size_t)r * E_];

  float C = __logf(atomicAdd(&slots[b * E_ + lane], 0.0f));

  for (int it = 1; it <= 8; ++it) {
    float q[8];
    float colacc = 0.f;
#pragma unroll
    for (int r = 0; r < 8; ++r) {
      const float p = __expf(t[r] - C);
      float s = p;
      s += __shfl_xor(s, 1);  s += __shfl_xor(s, 2);  s += __shfl_xor(s, 4);
      s += __shfl_xor(s, 8);  s += __shfl_xor(s, 16); s += __shfl_xor(s, 32);
      q[r] = p / s;
      colacc += q[r];
    }
    if (it < 8) {
      wsum[wv][lane] = colacc;
      __syncthreads();
      if (tid < 64) {
        const float tot = wsum[0][tid] + wsum[1][tid] + wsum[2][tid] + wsum[3][tid];
        atomicAdd(&slots[it * (B_ * E_) + b * E_ + tid], tot);
      }
      __threadfence();
      cg::this_grid().sync();
      if (tid < 64)
        cbuf[tid] = __logf(atomicAdd(&slots[it * (B_ * E_) + b * E_ + tid], 0.0f));
      __syncthreads();
      C += cbuf[lane];
    } else {
#pragma unroll
      for (int r = 0; r < 8; ++r) out[base + (size_t)r * E_] = q[r];
    }
  }
}

// ---------------------------------------------------------------------------
// Fallback per-iteration kernel (proven) — used only if cooperative launch
// is rejected; deterministic either way.
// ---------------------------------------------------------------------------
__global__ __launch_bounds__(256) void sinkhorn_iter(const float* __restrict__ t0,
                                                     float* __restrict__ slots,
                                                     float* __restrict__ out,
                                                     int it, int last) {
  const int tid = threadIdx.x;
  const int lane = tid & 63;
  const int wv = tid >> 6;
  const int b = blockIdx.x >> 8;
  const int chunk = blockIdx.x & 255;

  float C = __logf(slots[b * E_ + lane]);
  for (int j = 1; j < it; ++j) C += __logf(slots[j * (B_ * E_) + b * E_ + lane]);

  float colacc = 0.f;
  const int nbase = chunk * 32 + wv * 8;
#pragma unroll
  for (int i = 0; i < 8; ++i) {
    const int n = nbase + i;
    const float v = t0[((size_t)b * N_ + n) * E_ + lane];
    const float p = __expf(v - C);
    float s = p;
    s += __shfl_xor(s, 1);  s += __shfl_xor(s, 2);  s += __shfl_xor(s, 4);
    s += __shfl_xor(s, 8);  s += __shfl_xor(s, 16); s += __shfl_xor(s, 32);
    const float q = p / s;
    if (last) out[((size_t)b * N_ + n) * E_ + lane] = q;
    else      colacc += q;
  }
  if (!last) {
    __shared__ float wsum[4][64];
    wsum[wv][lane] = colacc;
    __syncthreads();
    if (tid < 64) {
      const float tot = wsum[0][tid] + wsum[1][tid] + wsum[2][tid] + wsum[3][tid];
      atomicAdd(&slots[it * (B_ * E_) + b * E_ + tid], tot);
    }
  }
}

// ---------------------------------------------------------------------------
extern "C" void kernel_launch(void* const* d_in, const int* in_sizes, int n_in,
                              void* d_out, int out_size, void* d_ws, size_t ws_size,
                              hipStream_t stream) {
  (void)in_sizes; (void)n_in; (void)out_size; (void)ws_size;
  const float* x = (const float*)d_in[0];
  const float* w = (const float*)d_in[1];
  float* out = (float*)d_out;                       // t0 lives here, overwritten in place
  float* slots = (float*)d_ws;                      // [8][B_][E_] = 8 KiB
  _Float16* w16 = (_Float16*)((char*)d_ws + 8192);  // 512 KiB

  hipMemsetAsync(slots, 0, 8 * B_ * E_ * sizeof(float), stream);
  convert_w<<<(E_ * D_) / 1024, 256, 0, stream>>>(w, w16);
  gemm_log<<<M_ / 32, 256, 0, stream>>>(x, w16, out, slots);

  const float* t0c = out;
  void* args[] = { (void*)&t0c, (void*)&slots, (void*)&out };
  hipError_t e = hipLaunchCooperativeKernel((void*)sinkhorn_all, dim3(B_ * 256),
                                            dim3(256), args, 0, stream);
  if (e != hipSuccess) {
    for (int it = 1; it <= 8; ++it)
      sinkhorn_iter<<<B_ * 256, 256, 0, stream>>>(out, slots, out, it, it == 8 ? 1 : 0);
  }
}